// Round 3
// baseline (189.464 us; speedup 1.0000x reference)
//
#include <hip/hip_runtime.h>

// DCT_18769007084406: RGB->YCbCr (1x1 conv) -> 8x8 stride-8 block DCT
// (grouped conv) -> 32x repeated (t-min)/d normalization (closed form).
//
// R3: persistent blocks + async global->LDS DMA pipelined across bands.
// Grid 768 (3 blocks/CU via 48KB LDS), 192 threads (3 waves = 3 channels).
// Per band: phase A reads RGB rows from LDS, converts YCbCr, row-DCT into
// registers; barrier; issue DMA for the NEXT band into the same LDS buffer
// (async, no VGPR round-trip); phase B col-DCT + fused norm + coalesced
// stores hides the DMA latency; barrier (compiler drains vmcnt) -> next band.

#define HW 512
#define CHST (HW * HW)       // channel stride in x (floats)
#define NBAND 2048           // 32 batches * 64 block-rows
#define GRID 768             // 3 blocks/CU * 256 CUs
#define NPAIR 6144           // 32 * 192 (b, out-channel) pairs
#define EPS 1e-6f

#define GLOBAL_AS __attribute__((address_space(1)))
#define LDS_AS    __attribute__((address_space(3)))

// basis[u][i] = c(u) * cos(pi*u*(i+0.5)/8); c(0)=sqrt(1/8), c(u>0)=0.5
static constexpr float BASIS[8][8] = {
  { 0.35355339059327373f, 0.35355339059327373f, 0.35355339059327373f, 0.35355339059327373f,
    0.35355339059327373f, 0.35355339059327373f, 0.35355339059327373f, 0.35355339059327373f },
  { 0.49039264020161522f, 0.41573480615127262f, 0.27778511650980114f, 0.09754516100806412f,
   -0.09754516100806412f,-0.27778511650980114f,-0.41573480615127262f,-0.49039264020161522f },
  { 0.46193976625564337f, 0.19134171618254492f,-0.19134171618254492f,-0.46193976625564337f,
   -0.46193976625564337f,-0.19134171618254492f, 0.19134171618254492f, 0.46193976625564337f },
  { 0.41573480615127262f,-0.09754516100806412f,-0.49039264020161522f,-0.27778511650980114f,
    0.27778511650980114f, 0.49039264020161522f, 0.09754516100806412f,-0.41573480615127262f },
  { 0.35355339059327373f,-0.35355339059327373f,-0.35355339059327373f, 0.35355339059327373f,
    0.35355339059327373f,-0.35355339059327373f,-0.35355339059327373f, 0.35355339059327373f },
  { 0.27778511650980114f,-0.49039264020161522f, 0.09754516100806412f, 0.41573480615127262f,
   -0.41573480615127262f,-0.09754516100806412f, 0.49039264020161522f,-0.27778511650980114f },
  { 0.19134171618254492f,-0.46193976625564337f, 0.46193976625564337f,-0.19134171618254492f,
   -0.19134171618254492f, 0.46193976625564337f,-0.46193976625564337f, 0.19134171618254492f },
  { 0.09754516100806412f,-0.27778511650980114f, 0.41573480615127262f,-0.49039264020161522f,
    0.49039264020161522f,-0.41573480615127262f, 0.27778511650980114f,-0.09754516100806412f }
};

// t_32 = a^32 * t0 - min * sum_{k=1..32} a^k, a = 1/(max-min+eps)
__global__ void precomp_norm(const float* __restrict__ max_,
                             const float* __restrict__ min_,
                             float* __restrict__ so) {
    int i = blockIdx.x * 256 + threadIdx.x;
    if (i >= NPAIR) return;
    float mn = min_[i], mx = max_[i];
    float d = mx - mn + EPS;
    float a = 1.0f / d;
    float a2 = a * a, a4 = a2 * a2, a8 = a4 * a4, a16 = a8 * a8, a32 = a16 * a16;
    float geo = a * (1.0f - a32) / (1.0f - a);   // sum_{k=1..32} a^k
    so[2 * i]     = a32;
    so[2 * i + 1] = -mn * geo;
}

template <bool USE_WS>
__global__ __launch_bounds__(192)
void dct_kernel(const float* __restrict__ x,
                const float* __restrict__ ycbcr_w,
                const float* __restrict__ so,
                const float* __restrict__ max_,
                const float* __restrict__ min_,
                float* __restrict__ out) {
    // raw RGB band: [3 ch][8 rows][512 cols] floats = 48 KB
    __shared__ float ylds[3 * 8 * HW];

    const int t    = threadIdx.x;
    const int w    = t >> 6;       // wave id: channel for DMA AND for compute
    const int lane = t & 63;       // lane = block-col (compute), DMA sub-offset

    // wave-uniform YCbCr weights (row w of the 3x3 matrix)
    const float w0 = ycbcr_w[w * 3 + 0];
    const float w1 = ycbcr_w[w * 3 + 1];
    const float w2 = ycbcr_w[w * 3 + 2];

    // Issue async DMA of band m's RGB into LDS. Wave w stages channel w:
    // 16 chunks of 1 KB (64 lanes x 16 B). LDS dest is wave-uniform base;
    // HW adds lane*16.
    auto prefetch = [&](int m) {
        const int b  = m >> 6;
        const int by = m & 63;
        const float* g0 = x + ((size_t)(b * 3 + w)) * CHST + (size_t)(by * 8) * HW + lane * 4;
        float* l0 = ylds + w * 4096;
#pragma unroll
        for (int k = 0; k < 16; ++k) {
            __builtin_amdgcn_global_load_lds(
                (const GLOBAL_AS void*)(g0 + k * 256),
                (LDS_AS void*)(l0 + k * 256), 16, 0, 0);
        }
    };

    const int m0 = blockIdx.x;
    prefetch(m0);
    __syncthreads();   // compiler drains vmcnt before s_barrier -> band ready

    for (int m = m0; m < NBAND; m += GRID) {
        const int b  = m >> 6;
        const int by = m & 63;
        const int bx = lane;

        // ---------- phase A: YCbCr + row-DCT from LDS ----------
        const float* rl = ylds + bx * 8;             // R rows
        const float* gl = rl + 4096;                 // G rows
        const float* bl = rl + 8192;                 // B rows

        float tmp[8][8];   // tmp[u][j] = sum_i basis[u][i] * y[i][j]
#pragma unroll
        for (int u = 0; u < 8; ++u)
#pragma unroll
            for (int j = 0; j < 8; ++j) tmp[u][j] = 0.0f;

#pragma unroll
        for (int i = 0; i < 8; ++i) {
            float R[8], G[8], Bl[8], y[8];
            *(float4*)(&R[0])  = *(const float4*)(rl + i * HW);
            *(float4*)(&R[4])  = *(const float4*)(rl + i * HW + 4);
            *(float4*)(&G[0])  = *(const float4*)(gl + i * HW);
            *(float4*)(&G[4])  = *(const float4*)(gl + i * HW + 4);
            *(float4*)(&Bl[0]) = *(const float4*)(bl + i * HW);
            *(float4*)(&Bl[4]) = *(const float4*)(bl + i * HW + 4);
#pragma unroll
            for (int j = 0; j < 8; ++j)
                y[j] = fmaf(w0, R[j], fmaf(w1, G[j], w2 * Bl[j]));
#pragma unroll
            for (int u = 0; u < 8; ++u) {
                const float bu = BASIS[u][i];
#pragma unroll
                for (int j = 0; j < 8; ++j)
                    tmp[u][j] = fmaf(bu, y[j], tmp[u][j]);
            }
        }
        __syncthreads();   // all LDS reads of band m done

        // ---------- prefetch band m+GRID (overlaps phase B) ----------
        if (m + GRID < NBAND) prefetch(m + GRID);

        // ---------- phase B: col-DCT + norm + coalesced stores ----------
        const int obase = b * 192 + w * 64;   // first output channel (b, o)
        float* op = out + ((size_t)obase * 64 + by) * 64 + bx;

#pragma unroll
        for (int u = 0; u < 8; ++u) {
#pragma unroll
            for (int v = 0; v < 8; ++v) {
                float acc = tmp[u][0] * BASIS[v][0];
#pragma unroll
                for (int j = 1; j < 8; ++j)
                    acc = fmaf(tmp[u][j], BASIS[v][j], acc);
                const int k = u * 8 + v;
                float s, o;
                if (USE_WS) {
                    s = so[(obase + k) * 2];       // wave-uniform -> s_load
                    o = so[(obase + k) * 2 + 1];
                } else {
                    float mn = min_[obase + k], mx = max_[obase + k];
                    float d  = mx - mn + EPS;
                    float a  = 1.0f / d;
                    float a2 = a * a, a4 = a2 * a2, a8 = a4 * a4, a16 = a8 * a8, a32 = a16 * a16;
                    s = a32;
                    o = -mn * (a * (1.0f - a32) / (1.0f - a));
                }
                op[(size_t)k * 4096] = fmaf(s, acc, o);  // lanes consecutive in bx
            }
        }

        __syncthreads();   // drains own vmcnt (DMA) -> band m+GRID ready
    }
}

extern "C" void kernel_launch(void* const* d_in, const int* in_sizes, int n_in,
                              void* d_out, int out_size, void* d_ws, size_t ws_size,
                              hipStream_t stream) {
    const float* x    = (const float*)d_in[0];
    const float* max_ = (const float*)d_in[1];
    const float* min_ = (const float*)d_in[2];
    const float* yw   = (const float*)d_in[3];
    float* out = (float*)d_out;
    float* so  = (float*)d_ws;

    const bool use_ws = (ws_size >= (size_t)NPAIR * 2 * sizeof(float));
    if (use_ws) {
        precomp_norm<<<(NPAIR + 255) / 256, 256, 0, stream>>>(max_, min_, so);
        dct_kernel<true><<<GRID, 192, 0, stream>>>(x, yw, so, max_, min_, out);
    } else {
        dct_kernel<false><<<GRID, 192, 0, stream>>>(x, yw, nullptr, max_, min_, out);
    }
}